// Round 1
// baseline (2615.220 us; speedup 1.0000x reference)
//
#include <hip/hip_runtime.h>
#include <stdint.h>

typedef unsigned short u16;
typedef __attribute__((ext_vector_type(8))) short short8;
typedef __attribute__((ext_vector_type(8))) unsigned short u16x8;
typedef __attribute__((ext_vector_type(4))) float f32x4;

#define NN    10000   // nodes
#define NP    10016   // node dim padded to 32 (K of big GEMM)
#define MPADJ 10112   // adj rows padded to 128 (79*128)
#define BB    4       // batch
#define HH    128
#define FIN   963
#define KIN   992     // FIN padded to 32
#define MR    40000   // B*N rows of activations
#define MRP   40064   // padded to 128 (313*128)

__device__ __forceinline__ u16 f2bf(float f) {
  uint32_t u = __builtin_bit_cast(uint32_t, f);
  u += 0x7FFFu + ((u >> 16) & 1u);   // RNE; inputs are finite
  return (u16)(u >> 16);
}

__device__ __forceinline__ void gl2lds16(const void* g, void* l) {
  __builtin_amdgcn_global_load_lds((const __attribute__((address_space(1))) uint32_t*)g,
                                   (__attribute__((address_space(3))) uint32_t*)l, 16, 0, 0);
}

// ---------------- conversion / padding kernels ----------------

__global__ void conv_adj(const float* __restrict__ adj, u16* __restrict__ adjB) {
  int row = blockIdx.y;
  int j8 = blockIdx.x * 256 + threadIdx.x;     // 8-element column group
  if (j8 >= NP / 8) return;
  int j = j8 * 8;
  u16x8 o = {};
  if (row < NN && j < NN) {
    const float* p = adj + (size_t)row * NN + j;
    float4 a = *(const float4*)p;
    float4 b = *(const float4*)(p + 4);
    o[0] = f2bf(a.x); o[1] = f2bf(a.y); o[2] = f2bf(a.z); o[3] = f2bf(a.w);
    o[4] = f2bf(b.x); o[5] = f2bf(b.y); o[6] = f2bf(b.z); o[7] = f2bf(b.w);
  }
  *(u16x8*)(adjB + (size_t)row * NP + j) = o;
}

__global__ void conv_xin(const float* __restrict__ xin, u16* __restrict__ xinB) {
  int r = blockIdx.y;
  int f = blockIdx.x * 256 + threadIdx.x;
  if (f >= KIN) return;
  float v = 0.f;
  if (r < MR && f < FIN) v = xin[(size_t)r * FIN + f];
  xinB[(size_t)r * KIN + f] = f2bf(v);
}

__global__ void conv_w1(const float* __restrict__ wi, const float* __restrict__ lwi,
                        u16* __restrict__ Wt) {
  int tid = blockIdx.x * 256 + threadIdx.x;    // 256*KIN
  if (tid >= 256 * KIN) return;
  int c = tid / KIN, k = tid - c * KIN;
  float v = 0.f;
  if (k < FIN) v = (c < HH) ? wi[(size_t)k * HH + c] : lwi[(size_t)k * HH + (c - HH)];
  Wt[tid] = f2bf(v);
}

__global__ void conv_wres(const float* __restrict__ w1, const float* __restrict__ lw1,
                          const float* __restrict__ w2, const float* __restrict__ lw2,
                          u16* __restrict__ Wt) {
  int tid = blockIdx.x * 256 + threadIdx.x;    // 6*256*128
  if (tid >= 6 * 256 * HH) return;
  int l = tid / (256 * HH);
  int rem = tid - l * (256 * HH);
  int c = rem / HH, k = rem - c * HH;
  int blk = l >> 1;
  const float* W  = (l & 1) ? w2  : w1;
  const float* LW = (l & 1) ? lw2 : lw1;
  float v = (c < HH) ? W[((size_t)blk * HH + k) * HH + c]
                     : LW[((size_t)blk * HH + k) * HH + (c - HH)];
  Wt[tid] = f2bf(v);
}

__global__ void pad_zero(u16* tT, u16* xB, u16* h1B, u16* t3) {
  int tid = blockIdx.x * 256 + threadIdx.x;
  if (tid < 8192) {                         // tT pad cols [10000,10016) for 512 rows
    tT[(size_t)(tid >> 4) * NP + NN + (tid & 15)] = 0;
  } else if (tid < 16384) {                 // xB pad rows
    xB[(size_t)MR * HH + (tid - 8192)] = 0;
  } else if (tid < 24576) {                 // h1B pad rows
    h1B[(size_t)MR * HH + (tid - 16384)] = 0;
  } else if (tid < 24832) {                 // t3 pad cols
    int t = tid - 24576;
    t3[(size_t)(t >> 4) * NP + NN + (t & 15)] = 0;
  }
}

// ---------------- GEMM kernels (A * B^T form; both operands [row][k]) ----------------

// Big: A=adjB (MPADJ x NP), Bt=tT (512 x NP), out partials P[s] (NN x 512) fp32. split-K=3.
__global__ __launch_bounds__(256) void gemm_big(const u16* __restrict__ A,
                                                const u16* __restrict__ Bt,
                                                float* __restrict__ P) {
  __shared__ u16 As[128 * 32];
  __shared__ u16 Bs[128 * 32];
  int mt_ = blockIdx.x, nt_ = blockIdx.y, s = blockIdx.z;
  int kt0 = (313 * s) / 3, kt1 = (313 * (s + 1)) / 3;
  int tid = threadIdx.x;
  int wave = tid >> 6, lane = tid & 63;
  int wm = wave >> 1, wn = wave & 1;
  int lr = lane >> 2, lc = (lane & 3) * 8;
  int ml = lane & 15, q = lane >> 4;

  const u16* Abase = A + (size_t)(mt_ * 128 + wave * 16 + lr) * NP + lc;
  const u16* Bbase = Bt + (size_t)(nt_ * 128 + wave * 16 + lr) * NP + lc;
  u16* lA = &As[(wave * 16) * 32];
  u16* lB = &Bs[(wave * 16) * 32];

  f32x4 acc[4][4] = {};
  for (int kt = kt0; kt < kt1; ++kt) {
    int k0 = kt * 32;
    __syncthreads();
    gl2lds16(Abase + k0, lA);
    gl2lds16(Abase + k0 + (size_t)64 * NP, lA + 64 * 32);
    gl2lds16(Bbase + k0, lB);
    gl2lds16(Bbase + k0 + (size_t)64 * NP, lB + 64 * 32);
    __syncthreads();
    short8 af[4], bf[4];
#pragma unroll
    for (int i = 0; i < 4; i++) af[i] = *(const short8*)&As[(wm * 64 + i * 16 + ml) * 32 + q * 8];
#pragma unroll
    for (int i = 0; i < 4; i++) bf[i] = *(const short8*)&Bs[(wn * 64 + i * 16 + ml) * 32 + q * 8];
#pragma unroll
    for (int i = 0; i < 4; i++)
#pragma unroll
      for (int j = 0; j < 4; j++)
        acc[i][j] = __builtin_amdgcn_mfma_f32_16x16x32_bf16(af[i], bf[j], acc[i][j], 0, 0, 0);
  }
  float* Ps = P + (size_t)s * NN * 512;
#pragma unroll
  for (int i = 0; i < 4; i++) {
    int row0 = mt_ * 128 + wm * 64 + i * 16 + q * 4;
#pragma unroll
    for (int j = 0; j < 4; j++) {
      int col = nt_ * 128 + wn * 64 + j * 16 + ml;
#pragma unroll
      for (int r = 0; r < 4; r++) {
        int row = row0 + r;
        if (row < NN) Ps[(size_t)row * 512 + col] = acc[i][j][r];
      }
    }
  }
}

// Small: A = activations (MRP x lda bf16), Wt = [W|LW]^T (256 x lda). Tile 128x128.
// blockIdx.y==0 -> t half (write tT[b*128+h][n] bf16), ==1 -> u half (+bias, fp32 (B,N,H)).
__global__ __launch_bounds__(256) void gemm_small(const u16* __restrict__ A, int lda,
                                                  const u16* __restrict__ Wt, int ktiles,
                                                  const float* __restrict__ bias,
                                                  u16* __restrict__ tT, float* __restrict__ u) {
  __shared__ u16 As[128 * 32];
  __shared__ u16 Bs[128 * 32];
  int mt_ = blockIdx.x, half = blockIdx.y;
  int tid = threadIdx.x;
  int wave = tid >> 6, lane = tid & 63;
  int wm = wave >> 1, wn = wave & 1;
  int lr = lane >> 2, lc = (lane & 3) * 8;
  int ml = lane & 15, q = lane >> 4;

  const u16* Abase = A + (size_t)(mt_ * 128 + wave * 16 + lr) * lda + lc;
  const u16* Bbase = Wt + (size_t)(half * 128 + wave * 16 + lr) * lda + lc;
  u16* lA = &As[(wave * 16) * 32];
  u16* lB = &Bs[(wave * 16) * 32];

  f32x4 acc[4][4] = {};
  for (int kt = 0; kt < ktiles; ++kt) {
    int k0 = kt * 32;
    __syncthreads();
    gl2lds16(Abase + k0, lA);
    gl2lds16(Abase + k0 + (size_t)64 * lda, lA + 64 * 32);
    gl2lds16(Bbase + k0, lB);
    gl2lds16(Bbase + k0 + (size_t)64 * lda, lB + 64 * 32);
    __syncthreads();
    short8 af[4], bf[4];
#pragma unroll
    for (int i = 0; i < 4; i++) af[i] = *(const short8*)&As[(wm * 64 + i * 16 + ml) * 32 + q * 8];
#pragma unroll
    for (int i = 0; i < 4; i++) bf[i] = *(const short8*)&Bs[(wn * 64 + i * 16 + ml) * 32 + q * 8];
#pragma unroll
    for (int i = 0; i < 4; i++)
#pragma unroll
      for (int j = 0; j < 4; j++)
        acc[i][j] = __builtin_amdgcn_mfma_f32_16x16x32_bf16(af[i], bf[j], acc[i][j], 0, 0, 0);
  }
#pragma unroll
  for (int i = 0; i < 4; i++) {
    int row0 = mt_ * 128 + wm * 64 + i * 16 + q * 4;
#pragma unroll
    for (int j = 0; j < 4; j++) {
      int col = wn * 64 + j * 16 + ml;     // 0..127 within half
#pragma unroll
      for (int r = 0; r < 4; r++) {
        int row = row0 + r;                // = b*NN + n
        if (row < MR) {
          if (half == 0) {
            int b = row / NN;
            int n = row - b * NN;
            tT[(size_t)(b * 128 + col) * NP + n] = f2bf(acc[i][j][r]);
          } else {
            u[(size_t)row * HH + col] = acc[i][j][r] + bias[col];
          }
        }
      }
    }
  }
}

// reduce split-K partials + u, apply activation/residual. layout linear in (n, b*128+h).
// mode 0: x=relu(v) -> xf,xB ; 1: h1=relu(v) -> xB(h1B) ; 2: x=(x+relu(v))*0.5 -> xf,xB ;
// 3: mode2 + write fp32 x to outx (d_out second output).
__global__ void reduce_act(const float* __restrict__ P, const float* __restrict__ u,
                           float* __restrict__ xf, u16* __restrict__ xB,
                           float* __restrict__ outx, int mode) {
  int tid = blockIdx.x * 256 + threadIdx.x;
  if (tid >= NN * 512) return;
  int n = tid >> 9, c = tid & 511;
  int b = c >> 7, h = c & 127;
  size_t uidx = (size_t)(b * NN + n) * HH + h;
  float v = P[tid] + P[5120000 + tid] + P[10240000 + tid] + u[uidx];
  v = v > 0.f ? v : 0.f;
  if (mode == 0) {
    xf[uidx] = v;
    xB[uidx] = f2bf(v);
  } else if (mode == 1) {
    xB[uidx] = f2bf(v);
  } else {
    float xn = (xf[uidx] + v) * 0.5f;
    xf[uidx] = xn;
    xB[uidx] = f2bf(xn);
    if (mode == 3) outx[uidx] = xn;
  }
}

// output layer small part: t3[c3][n] = x@out_w (bf16), u3[n*16+c3] = x@out_lw + out_b (fp32)
// c3 = b*4 + f, f<3 valid (f==3 columns zero).
__global__ void out_small(const float* __restrict__ x, const float* __restrict__ ow,
                          const float* __restrict__ olw, const float* __restrict__ ob,
                          u16* __restrict__ t3, float* __restrict__ u3) {
  int tid = blockIdx.x * 256 + threadIdx.x;
  if (tid >= NN * 16) return;
  int n = tid >> 4, c3 = tid & 15, b = c3 >> 2, f = c3 & 3;
  float tv = 0.f, uv = 0.f;
  if (f < 3) {
    const float* xr = x + (size_t)(b * NN + n) * HH;
    for (int k = 0; k < HH; k++) {
      float xv = xr[k];
      tv += xv * ow[k * 3 + f];
      uv += xv * olw[k * 3 + f];
    }
    uv += ob[f];
  }
  t3[(size_t)c3 * NP + n] = f2bf(tv);
  u3[tid] = uv;
}

// skinny GEMM: adjB (MPADJ x NP) * t3^T (16 x NP) -> P3[s] (NP x 16) fp32, split-K=2
__global__ __launch_bounds__(256) void gemm_skinny(const u16* __restrict__ A,
                                                   const u16* __restrict__ Bt,
                                                   float* __restrict__ P3) {
  __shared__ u16 As[64 * 32];
  __shared__ u16 Bs[16 * 32];
  int mt_ = blockIdx.x, s = blockIdx.y;
  int kt0 = (313 * s) / 2, kt1 = (313 * (s + 1)) / 2;
  int tid = threadIdx.x;
  int wave = tid >> 6, lane = tid & 63;
  int lr = lane >> 2, lc = (lane & 3) * 8;
  int ml = lane & 15, q = lane >> 4;

  const u16* Abase = A + (size_t)(mt_ * 64 + wave * 16 + lr) * NP + lc;
  const u16* Bbase = Bt + (size_t)lr * NP + lc;
  u16* lA = &As[(wave * 16) * 32];

  f32x4 acc = {};
  for (int kt = kt0; kt < kt1; ++kt) {
    int k0 = kt * 32;
    __syncthreads();
    gl2lds16(Abase + k0, lA);
    if (wave == 0) gl2lds16(Bbase + k0, &Bs[0]);
    __syncthreads();
    short8 af = *(const short8*)&As[(wave * 16 + ml) * 32 + q * 8];
    short8 bf = *(const short8*)&Bs[ml * 32 + q * 8];
    acc = __builtin_amdgcn_mfma_f32_16x16x32_bf16(af, bf, acc, 0, 0, 0);
  }
  float* Ps = P3 + (size_t)s * NP * 16;
  int row0 = mt_ * 64 + wave * 16 + q * 4;
#pragma unroll
  for (int r = 0; r < 4; r++) {
    int row = row0 + r;
    if (row < NN) Ps[(size_t)row * 16 + ml] = acc[r];
  }
}

__global__ void reduce3k(const float* __restrict__ P3, const float* __restrict__ u3,
                         float* __restrict__ out0) {
  int tid = blockIdx.x * 256 + threadIdx.x;
  if (tid >= NN * 12) return;
  int n = tid / 12;
  int rr = tid - n * 12;
  int b = rr / 3, f = rr - b * 3;
  int c3 = b * 4 + f;
  float v = P3[(size_t)n * 16 + c3] + P3[(size_t)NP * 16 + (size_t)n * 16 + c3] + u3[n * 16 + c3];
  out0[(size_t)(b * NN + n) * 3 + f] = v;
}

// ---------------- launch ----------------

extern "C" void kernel_launch(void* const* d_in, const int* in_sizes, int n_in,
                              void* d_out, int out_size, void* d_ws, size_t ws_size,
                              hipStream_t stream) {
  (void)in_sizes; (void)n_in; (void)out_size; (void)ws_size;
  const float* xin    = (const float*)d_in[0];
  const float* adj    = (const float*)d_in[1];
  const float* in_w   = (const float*)d_in[2];
  const float* in_lw  = (const float*)d_in[3];
  const float* in_b   = (const float*)d_in[4];
  const float* res_w1 = (const float*)d_in[5];
  const float* res_lw1= (const float*)d_in[6];
  const float* res_b1 = (const float*)d_in[7];
  const float* res_w2 = (const float*)d_in[8];
  const float* res_lw2= (const float*)d_in[9];
  const float* res_b2 = (const float*)d_in[10];
  const float* out_w  = (const float*)d_in[11];
  const float* out_lw = (const float*)d_in[12];
  const float* out_b  = (const float*)d_in[13];

  char* wsp = (char*)d_ws;
  size_t off = 0;
  auto alloc = [&](size_t bytes) -> char* {
    char* p = wsp + off;
    off += (bytes + 255) & ~(size_t)255;
    return p;
  };
  u16*   adjB  = (u16*)alloc((size_t)MPADJ * NP * 2);          // 202.6 MB
  char*  xinRg = alloc((size_t)MRP * KIN * 2);                 // 79.5 MB (aliased with P)
  u16*   xinB  = (u16*)xinRg;
  float* P     = (float*)xinRg;                                // 3*NN*512*4 = 61.4 MB <= region
  u16*   WcatT = (u16*)alloc((size_t)256 * KIN * 2);
  u16*   WresT = (u16*)alloc((size_t)6 * 256 * HH * 2);
  u16*   tT    = (u16*)alloc((size_t)512 * NP * 2);
  float* u     = (float*)alloc((size_t)MR * HH * 4);
  float* xf    = (float*)alloc((size_t)MR * HH * 4);
  u16*   xB    = (u16*)alloc((size_t)MRP * HH * 2);
  u16*   h1B   = (u16*)alloc((size_t)MRP * HH * 2);
  u16*   t3    = (u16*)alloc((size_t)16 * NP * 2);
  float* u3    = (float*)alloc((size_t)NN * 16 * 4);
  float* P3    = (float*)alloc((size_t)2 * NP * 16 * 4);

  float* out0 = (float*)d_out;
  float* out1 = (float*)d_out + (size_t)BB * NN * 3;

  // prep
  {
    dim3 g((NP / 8 + 255) / 256, MPADJ);
    conv_adj<<<g, 256, 0, stream>>>(adj, adjB);
  }
  {
    dim3 g((KIN + 255) / 256, MRP);
    conv_xin<<<g, 256, 0, stream>>>(xin, xinB);
  }
  conv_w1<<<(256 * KIN + 255) / 256, 256, 0, stream>>>(in_w, in_lw, WcatT);
  conv_wres<<<(6 * 256 * HH + 255) / 256, 256, 0, stream>>>(res_w1, res_lw1, res_w2, res_lw2, WresT);
  pad_zero<<<(24832 + 255) / 256, 256, 0, stream>>>(tT, xB, h1B, t3);

  dim3 gsmall(313, 2);
  dim3 gbig(79, 4, 3);
  int nred = (NN * 512 + 255) / 256;

  // layer 1 (K=992)
  gemm_small<<<gsmall, 256, 0, stream>>>(xinB, KIN, WcatT, KIN / 32, in_b, tT, u);
  gemm_big<<<gbig, 256, 0, stream>>>(adjB, tT, P);
  reduce_act<<<nred, 256, 0, stream>>>(P, u, xf, xB, nullptr, 0);

  // residual blocks
  for (int blk = 0; blk < 3; blk++) {
    gemm_small<<<gsmall, 256, 0, stream>>>(xB, HH, WresT + (size_t)(2 * blk) * 256 * HH,
                                           HH / 32, res_b1 + blk * HH, tT, u);
    gemm_big<<<gbig, 256, 0, stream>>>(adjB, tT, P);
    reduce_act<<<nred, 256, 0, stream>>>(P, u, nullptr, h1B, nullptr, 1);

    gemm_small<<<gsmall, 256, 0, stream>>>(h1B, HH, WresT + (size_t)(2 * blk + 1) * 256 * HH,
                                           HH / 32, res_b2 + blk * HH, tT, u);
    gemm_big<<<gbig, 256, 0, stream>>>(adjB, tT, P);
    reduce_act<<<nred, 256, 0, stream>>>(P, u, xf, xB, out1, (blk == 2) ? 3 : 2);
  }

  // output layer
  out_small<<<(NN * 16 + 255) / 256, 256, 0, stream>>>(xf, out_w, out_lw, out_b, t3, u3);
  {
    dim3 g(157, 2);
    gemm_skinny<<<g, 256, 0, stream>>>(adjB, t3, P3);
  }
  reduce3k<<<(NN * 12 + 255) / 256, 256, 0, stream>>>(P3, u3, out0);
}

// Round 2
// 2123.565 us; speedup vs baseline: 1.2315x; 1.2315x over previous
//
#include <hip/hip_runtime.h>
#include <stdint.h>

typedef unsigned short u16;
typedef __attribute__((ext_vector_type(8))) short short8;
typedef __attribute__((ext_vector_type(8))) unsigned short u16x8;
typedef __attribute__((ext_vector_type(4))) float f32x4;

#define NN    10000   // nodes
#define NP    10016   // node dim padded to 32 (K of big GEMM)
#define NKT   313     // NP/32 k-tiles
#define MPADJ 10112   // adj rows padded to 128 (79*128)
#define BB    4       // batch
#define HH    128
#define FIN   963
#define KIN   992     // FIN padded to 32
#define MR    40000   // B*N rows of activations
#define MRP   40064   // padded to 128 (313*128)

__device__ __forceinline__ u16 f2bf(float f) {
  uint32_t u = __builtin_bit_cast(uint32_t, f);
  u += 0x7FFFu + ((u >> 16) & 1u);   // RNE; inputs are finite
  return (u16)(u >> 16);
}

// lds_base must be wave-uniform; HW adds lane*16.
__device__ __forceinline__ void gl2lds16(const void* g, void* l) {
  __builtin_amdgcn_global_load_lds((const __attribute__((address_space(1))) uint32_t*)g,
                                   (__attribute__((address_space(3))) uint32_t*)l, 16, 0, 0);
}

// ---------------- conversion / packing kernels ----------------

// adjB packed: tile (mt,kt) -> contiguous 128x32 u16 at ((mt*313+kt)*4096)
__global__ void conv_adj(const float* __restrict__ adj, u16* __restrict__ adjP) {
  int mt = blockIdx.x, kt = blockIdx.y;
  int t = threadIdx.x;                 // 256
  int tr = t >> 1, ch = (t & 1) * 16;  // row in tile, 16-col half
  int row = mt * 128 + tr, col = kt * 32 + ch;
  u16x8 o0 = {}, o1 = {};
  if (row < NN && col < NN) {
    const float* p = adj + (size_t)row * NN + col;
    float4 a = *(const float4*)p;
    float4 b = *(const float4*)(p + 4);
    float4 c = *(const float4*)(p + 8);
    float4 d = *(const float4*)(p + 12);
    o0[0] = f2bf(a.x); o0[1] = f2bf(a.y); o0[2] = f2bf(a.z); o0[3] = f2bf(a.w);
    o0[4] = f2bf(b.x); o0[5] = f2bf(b.y); o0[6] = f2bf(b.z); o0[7] = f2bf(b.w);
    o1[0] = f2bf(c.x); o1[1] = f2bf(c.y); o1[2] = f2bf(c.z); o1[3] = f2bf(c.w);
    o1[4] = f2bf(d.x); o1[5] = f2bf(d.y); o1[6] = f2bf(d.z); o1[7] = f2bf(d.w);
  }
  u16* dst = adjP + ((size_t)mt * NKT + kt) * 4096 + tr * 32 + ch;
  *(u16x8*)dst = o0;
  *(u16x8*)(dst + 8) = o1;
}

__global__ void conv_xin(const float* __restrict__ xin, u16* __restrict__ xinB) {
  int r = blockIdx.y;
  int f = blockIdx.x * 256 + threadIdx.x;
  if (f >= KIN) return;
  float v = 0.f;
  if (r < MR && f < FIN) v = xin[(size_t)r * FIN + f];
  xinB[(size_t)r * KIN + f] = f2bf(v);
}

__global__ void conv_w1(const float* __restrict__ wi, const float* __restrict__ lwi,
                        u16* __restrict__ Wt) {
  int tid = blockIdx.x * 256 + threadIdx.x;    // 256*KIN
  if (tid >= 256 * KIN) return;
  int c = tid / KIN, k = tid - c * KIN;
  float v = 0.f;
  if (k < FIN) v = (c < HH) ? wi[(size_t)k * HH + c] : lwi[(size_t)k * HH + (c - HH)];
  Wt[tid] = f2bf(v);
}

__global__ void conv_wres(const float* __restrict__ w1, const float* __restrict__ lw1,
                          const float* __restrict__ w2, const float* __restrict__ lw2,
                          u16* __restrict__ Wt) {
  int tid = blockIdx.x * 256 + threadIdx.x;    // 6*256*128
  if (tid >= 6 * 256 * HH) return;
  int l = tid / (256 * HH);
  int rem = tid - l * (256 * HH);
  int c = rem / HH, k = rem - c * HH;
  int blk = l >> 1;
  const float* W  = (l & 1) ? w2  : w1;
  const float* LW = (l & 1) ? lw2 : lw1;
  float v = (c < HH) ? W[((size_t)blk * HH + k) * HH + c]
                     : LW[((size_t)blk * HH + k) * HH + (c - HH)];
  Wt[tid] = f2bf(v);
}

// zero pad regions of packed tT, xB, h1B, packed t3
__global__ void pad_zero(u16* tT, u16* xB, u16* h1B, u16* t3) {
  int tid = blockIdx.x * 256 + threadIdx.x;
  if (tid < 8192) {                         // tT: nodes [10000,10016) for all b,h
    int b = tid >> 11, rem = tid & 2047;
    int h = rem >> 4, k = rem & 15;
    tT[((size_t)(b * NKT + 312) * 128 + h) * 32 + 16 + k] = 0;
  } else if (tid < 16384) {                 // xB pad rows
    xB[(size_t)MR * HH + (tid - 8192)] = 0;
  } else if (tid < 24576) {                 // h1B pad rows
    h1B[(size_t)MR * HH + (tid - 16384)] = 0;
  } else if (tid < 24832) {                 // t3: nodes [10000,10016) for all c3
    int t = tid - 24576;
    int c3 = t >> 4, k = t & 15;
    t3[(size_t)(312 * 16 + c3) * 32 + 16 + k] = 0;
  }
}

// ---------------- GEMM kernels ----------------

// Big: A=adjB packed (79x313 tiles), Bt=tT packed (4x313 tiles of [128ch x 32node]).
// Block: 512 thr (8 waves, 2x4), out tile 128 rows x 256 cols. split-K=3.
__global__ __launch_bounds__(512, 4) void gemm_big(const u16* __restrict__ A,
                                                   const u16* __restrict__ Bt,
                                                   float* __restrict__ P) {
  __shared__ u16 As[128 * 32];
  __shared__ u16 Bs[256 * 32];
  int mt = blockIdx.x, ntb = blockIdx.y, s = blockIdx.z;
  int kt0 = (NKT * s) / 3, kt1 = (NKT * (s + 1)) / 3;
  int tid = threadIdx.x;
  int w = tid >> 6, lane = tid & 63;
  int wm = w >> 2, wn = w & 3;
  int ml = lane & 15, q = lane >> 4;

  const u16* pa = A + ((size_t)mt * NKT + kt0) * 4096 + w * 512 + lane * 8;
  int seg0 = w * 2, seg1 = w * 2 + 1;
  const u16* pb0 = Bt + ((size_t)(ntb * 2 + (seg0 >> 3)) * NKT + kt0) * 4096 + (seg0 & 7) * 512 + lane * 8;
  const u16* pb1 = Bt + ((size_t)(ntb * 2 + (seg1 >> 3)) * NKT + kt0) * 4096 + (seg1 & 7) * 512 + lane * 8;
  u16* lA  = As + w * 512;
  u16* lB0 = Bs + seg0 * 512;
  u16* lB1 = Bs + seg1 * 512;

  f32x4 acc[4][4] = {};
  for (int kt = kt0; kt < kt1; ++kt) {
    __syncthreads();
    gl2lds16(pa, lA);
    gl2lds16(pb0, lB0);
    gl2lds16(pb1, lB1);
    pa += 4096; pb0 += 4096; pb1 += 4096;
    __syncthreads();
    short8 af[4], bf[4];
#pragma unroll
    for (int i = 0; i < 4; i++) af[i] = *(const short8*)&As[(wm * 64 + i * 16 + ml) * 32 + q * 8];
#pragma unroll
    for (int j = 0; j < 4; j++) bf[j] = *(const short8*)&Bs[(wn * 64 + j * 16 + ml) * 32 + q * 8];
#pragma unroll
    for (int i = 0; i < 4; i++)
#pragma unroll
      for (int j = 0; j < 4; j++)
        acc[i][j] = __builtin_amdgcn_mfma_f32_16x16x32_bf16(af[i], bf[j], acc[i][j], 0, 0, 0);
  }
  float* Ps = P + (size_t)s * NN * 512;
#pragma unroll
  for (int i = 0; i < 4; i++) {
    int row0 = mt * 128 + wm * 64 + i * 16 + q * 4;
#pragma unroll
    for (int j = 0; j < 4; j++) {
      int col = ntb * 256 + wn * 64 + j * 16 + ml;
#pragma unroll
      for (int r = 0; r < 4; r++) {
        int row = row0 + r;
        if (row < NN) Ps[(size_t)row * 512 + col] = acc[i][j][r];
      }
    }
  }
}

// Small: A = activations (MRP x lda bf16 row-major), Wt = [W|LW]^T (256 x lda). Tile 128x128.
// half==0 -> t half (write packed tT), ==1 -> u half (+bias, fp32 (B,N,H)).
__global__ __launch_bounds__(256) void gemm_small(const u16* __restrict__ A, int lda,
                                                  const u16* __restrict__ Wt, int ktiles,
                                                  const float* __restrict__ bias,
                                                  u16* __restrict__ tT, float* __restrict__ u) {
  __shared__ u16 As[128 * 32];
  __shared__ u16 Bs[128 * 32];
  int mt_ = blockIdx.x, half = blockIdx.y;
  int tid = threadIdx.x;
  int wave = tid >> 6, lane = tid & 63;
  int wm = wave >> 1, wn = wave & 1;
  int lr = lane >> 2, lc = (lane & 3) * 8;
  int ml = lane & 15, q = lane >> 4;

  const u16* Abase = A + (size_t)(mt_ * 128 + wave * 16 + lr) * lda + lc;
  const u16* Bbase = Wt + (size_t)(half * 128 + wave * 16 + lr) * lda + lc;
  u16* lA = &As[(wave * 16) * 32];
  u16* lB = &Bs[(wave * 16) * 32];

  f32x4 acc[4][4] = {};
  for (int kt = 0; kt < ktiles; ++kt) {
    int k0 = kt * 32;
    __syncthreads();
    gl2lds16(Abase + k0, lA);
    gl2lds16(Abase + k0 + (size_t)64 * lda, lA + 64 * 32);
    gl2lds16(Bbase + k0, lB);
    gl2lds16(Bbase + k0 + (size_t)64 * lda, lB + 64 * 32);
    __syncthreads();
    short8 af[4], bf[4];
#pragma unroll
    for (int i = 0; i < 4; i++) af[i] = *(const short8*)&As[(wm * 64 + i * 16 + ml) * 32 + q * 8];
#pragma unroll
    for (int i = 0; i < 4; i++) bf[i] = *(const short8*)&Bs[(wn * 64 + i * 16 + ml) * 32 + q * 8];
#pragma unroll
    for (int i = 0; i < 4; i++)
#pragma unroll
      for (int j = 0; j < 4; j++)
        acc[i][j] = __builtin_amdgcn_mfma_f32_16x16x32_bf16(af[i], bf[j], acc[i][j], 0, 0, 0);
  }
#pragma unroll
  for (int i = 0; i < 4; i++) {
    int row0 = mt_ * 128 + wm * 64 + i * 16 + q * 4;
#pragma unroll
    for (int j = 0; j < 4; j++) {
      int col = wn * 64 + j * 16 + ml;     // 0..127 within half
#pragma unroll
      for (int r = 0; r < 4; r++) {
        int row = row0 + r;                // = b*NN + n
        if (row < MR) {
          if (half == 0) {
            int b = row / NN;
            int n = row - b * NN;
            tT[((size_t)(b * NKT + (n >> 5)) * 128 + col) * 32 + (n & 31)] = f2bf(acc[i][j][r]);
          } else {
            u[(size_t)row * HH + col] = acc[i][j][r] + bias[col];
          }
        }
      }
    }
  }
}

// reduce split-K partials + u, apply activation/residual. tid linear in (n, b*128+h).
__global__ void reduce_act(const float* __restrict__ P, const float* __restrict__ u,
                           float* __restrict__ xf, u16* __restrict__ xB,
                           float* __restrict__ outx, int mode) {
  int tid = blockIdx.x * 256 + threadIdx.x;
  if (tid >= NN * 512) return;
  int n = tid >> 9, c = tid & 511;
  int b = c >> 7, h = c & 127;
  size_t uidx = (size_t)(b * NN + n) * HH + h;
  float v = P[tid] + P[5120000 + tid] + P[10240000 + tid] + u[uidx];
  v = v > 0.f ? v : 0.f;
  if (mode == 0) {
    xf[uidx] = v;
    xB[uidx] = f2bf(v);
  } else if (mode == 1) {
    xB[uidx] = f2bf(v);
  } else {
    float xn = (xf[uidx] + v) * 0.5f;
    xf[uidx] = xn;
    xB[uidx] = f2bf(xn);
    if (mode == 3) outx[uidx] = xn;
  }
}

// output layer small part: t3 packed [kt][16x32]; u3[n*16+c3] = x@out_lw + out_b (fp32)
__global__ void out_small(const float* __restrict__ x, const float* __restrict__ ow,
                          const float* __restrict__ olw, const float* __restrict__ ob,
                          u16* __restrict__ t3, float* __restrict__ u3) {
  int tid = blockIdx.x * 256 + threadIdx.x;
  if (tid >= NN * 16) return;
  int n = tid >> 4, c3 = tid & 15, b = c3 >> 2, f = c3 & 3;
  float tv = 0.f, uv = 0.f;
  if (f < 3) {
    const float* xr = x + (size_t)(b * NN + n) * HH;
    for (int k = 0; k < HH; k++) {
      float xv = xr[k];
      tv += xv * ow[k * 3 + f];
      uv += xv * olw[k * 3 + f];
    }
    uv += ob[f];
  }
  t3[((size_t)(n >> 5) * 16 + c3) * 32 + (n & 31)] = f2bf(tv);
  u3[tid] = uv;
}

// skinny GEMM: adjB packed * t3 packed (16xNP) -> P3[s] (NP x 16) fp32, split-K=4
__global__ __launch_bounds__(256) void gemm_skinny(const u16* __restrict__ A,
                                                   const u16* __restrict__ Bt,
                                                   float* __restrict__ P3) {
  __shared__ u16 As[128 * 32];
  __shared__ u16 Bs[16 * 32];
  int mt = blockIdx.x, s = blockIdx.y;
  int kt0 = (NKT * s) / 4, kt1 = (NKT * (s + 1)) / 4;
  int tid = threadIdx.x;
  int w = tid >> 6, lane = tid & 63;
  int ml = lane & 15, q = lane >> 4;

  const u16* pa = A + ((size_t)mt * NKT + kt0) * 4096 + w * 512 + lane * 8;
  const u16* pb = Bt + (size_t)kt0 * 512 + lane * 8;
  u16* lA0 = As + w * 512;
  u16* lA1 = As + 2048 + w * 512;

  f32x4 acc[2] = {};
  for (int kt = kt0; kt < kt1; ++kt) {
    __syncthreads();
    gl2lds16(pa, lA0);
    gl2lds16(pa + 2048, lA1);
    if (w == 0) gl2lds16(pb, Bs);
    pa += 4096; pb += 512;
    __syncthreads();
    short8 bf = *(const short8*)&Bs[ml * 32 + q * 8];
#pragma unroll
    for (int i = 0; i < 2; i++) {
      short8 af = *(const short8*)&As[(w * 32 + i * 16 + ml) * 32 + q * 8];
      acc[i] = __builtin_amdgcn_mfma_f32_16x16x32_bf16(af, bf, acc[i], 0, 0, 0);
    }
  }
  float* Ps = P3 + (size_t)s * NP * 16;
#pragma unroll
  for (int i = 0; i < 2; i++) {
    int row0 = mt * 128 + w * 32 + i * 16 + q * 4;
#pragma unroll
    for (int r = 0; r < 4; r++) {
      int row = row0 + r;
      if (row < NN) Ps[(size_t)row * 16 + ml] = acc[i][r];
    }
  }
}

__global__ void reduce3k(const float* __restrict__ P3, const float* __restrict__ u3,
                         float* __restrict__ out0) {
  int tid = blockIdx.x * 256 + threadIdx.x;
  if (tid >= NN * 12) return;
  int n = tid / 12;
  int rr = tid - n * 12;
  int b = rr / 3, f = rr - b * 3;
  int c3 = b * 4 + f;
  size_t stride = (size_t)NP * 16;
  float v = P3[(size_t)n * 16 + c3] + P3[stride + n * 16 + c3]
          + P3[2 * stride + n * 16 + c3] + P3[3 * stride + n * 16 + c3]
          + u3[n * 16 + c3];
  out0[(size_t)(b * NN + n) * 3 + f] = v;
}

// ---------------- launch ----------------

extern "C" void kernel_launch(void* const* d_in, const int* in_sizes, int n_in,
                              void* d_out, int out_size, void* d_ws, size_t ws_size,
                              hipStream_t stream) {
  (void)in_sizes; (void)n_in; (void)out_size; (void)ws_size;
  const float* xin    = (const float*)d_in[0];
  const float* adj    = (const float*)d_in[1];
  const float* in_w   = (const float*)d_in[2];
  const float* in_lw  = (const float*)d_in[3];
  const float* in_b   = (const float*)d_in[4];
  const float* res_w1 = (const float*)d_in[5];
  const float* res_lw1= (const float*)d_in[6];
  const float* res_b1 = (const float*)d_in[7];
  const float* res_w2 = (const float*)d_in[8];
  const float* res_lw2= (const float*)d_in[9];
  const float* res_b2 = (const float*)d_in[10];
  const float* out_w  = (const float*)d_in[11];
  const float* out_lw = (const float*)d_in[12];
  const float* out_b  = (const float*)d_in[13];

  char* wsp = (char*)d_ws;
  size_t off = 0;
  auto alloc = [&](size_t bytes) -> char* {
    char* p = wsp + off;
    off += (bytes + 255) & ~(size_t)255;
    return p;
  };
  u16*   adjB  = (u16*)alloc((size_t)79 * NKT * 4096 * 2);     // 202.6 MB packed
  char*  xinRg = alloc((size_t)MRP * KIN * 2);                 // 79.5 MB (aliased with P)
  u16*   xinB  = (u16*)xinRg;
  float* P     = (float*)xinRg;                                // 3*NN*512*4 = 61.4 MB <= region
  u16*   WcatT = (u16*)alloc((size_t)256 * KIN * 2);
  u16*   WresT = (u16*)alloc((size_t)6 * 256 * HH * 2);
  u16*   tT    = (u16*)alloc((size_t)4 * NKT * 4096 * 2);      // packed 512 x NP
  float* u     = (float*)alloc((size_t)MR * HH * 4);
  float* xf    = (float*)alloc((size_t)MR * HH * 4);
  u16*   xB    = (u16*)alloc((size_t)MRP * HH * 2);
  u16*   h1B   = (u16*)alloc((size_t)MRP * HH * 2);
  u16*   t3    = (u16*)alloc((size_t)NKT * 16 * 32 * 2);       // packed 16 x NP
  float* u3    = (float*)alloc((size_t)NN * 16 * 4);
  float* P3    = (float*)alloc((size_t)4 * NP * 16 * 4);

  float* out0 = (float*)d_out;
  float* out1 = (float*)d_out + (size_t)BB * NN * 3;

  // prep
  {
    dim3 g(79, NKT);
    conv_adj<<<g, 256, 0, stream>>>(adj, adjB);
  }
  {
    dim3 g((KIN + 255) / 256, MRP);
    conv_xin<<<g, 256, 0, stream>>>(xin, xinB);
  }
  conv_w1<<<(256 * KIN + 255) / 256, 256, 0, stream>>>(in_w, in_lw, WcatT);
  conv_wres<<<(6 * 256 * HH + 255) / 256, 256, 0, stream>>>(res_w1, res_lw1, res_w2, res_lw2, WresT);
  pad_zero<<<(24832 + 255) / 256, 256, 0, stream>>>(tT, xB, h1B, t3);

  dim3 gsmall(313, 2);
  dim3 gbig(79, 2, 3);
  int nred = (NN * 512 + 255) / 256;

  // layer 1 (K=992)
  gemm_small<<<gsmall, 256, 0, stream>>>(xinB, KIN, WcatT, KIN / 32, in_b, tT, u);
  gemm_big<<<gbig, 512, 0, stream>>>(adjB, tT, P);
  reduce_act<<<nred, 256, 0, stream>>>(P, u, xf, xB, nullptr, 0);

  // residual blocks
  for (int blk = 0; blk < 3; blk++) {
    gemm_small<<<gsmall, 256, 0, stream>>>(xB, HH, WresT + (size_t)(2 * blk) * 256 * HH,
                                           HH / 32, res_b1 + blk * HH, tT, u);
    gemm_big<<<gbig, 512, 0, stream>>>(adjB, tT, P);
    reduce_act<<<nred, 256, 0, stream>>>(P, u, nullptr, h1B, nullptr, 1);

    gemm_small<<<gsmall, 256, 0, stream>>>(h1B, HH, WresT + (size_t)(2 * blk + 1) * 256 * HH,
                                           HH / 32, res_b2 + blk * HH, tT, u);
    gemm_big<<<gbig, 512, 0, stream>>>(adjB, tT, P);
    reduce_act<<<nred, 256, 0, stream>>>(P, u, xf, xB, out1, (blk == 2) ? 3 : 2);
  }

  // output layer
  out_small<<<(NN * 16 + 255) / 256, 256, 0, stream>>>(xf, out_w, out_lw, out_b, t3, u3);
  {
    dim3 g(79, 4);
    gemm_skinny<<<g, 256, 0, stream>>>(adjB, t3, P3);
  }
  reduce3k<<<(NN * 12 + 255) / 256, 256, 0, stream>>>(P3, u3, out0);
}